// Round 3
// baseline (407.046 us; speedup 1.0000x reference)
//
#include <hip/hip_runtime.h>
#include <cfloat>

#define HH 64
#define WW 64
#define NKEYS 17
#define CCH 32
#define BG_W 10.0f

typedef unsigned long long u64;

struct VI { float v; int i; };
// strict <: keeps left on ties. Call with left = lower index.
__device__ inline VI vimin(VI a, VI b) { return (b.v < a.v) ? b : a; }

__device__ inline VI row4min(const float4& v, int i0) {
    VI a = {v.x, i0}, b = {v.y, i0 + 1}, c = {v.z, i0 + 2}, d = {v.w, i0 + 3};
    return vimin(vimin(a, b), vimin(c, d));
}

__device__ inline void wave_argmin(float &v, int &i) {
    #pragma unroll
    for (int off = 32; off > 0; off >>= 1) {
        float ov = __shfl_down(v, off, 64);
        int   oi = __shfl_down(i, off, 64);
        if (ov < v || (ov == v && oi < i)) { v = ov; i = oi; }
    }
}

__device__ inline u64 packvi(float v, int i) {
    // wdist >= 0 so float bits are monotone: u64 order == (value, index) lex order
    return ((u64)__float_as_uint(v) << 32) | (unsigned int)i;
}

// block argmin -> *slot. Leading barrier protects s_rv/s_ri reuse.
__device__ inline void block_argmin_slot(float v, int i, int tid,
                                         float* s_rv, int* s_ri, u64* slot) {
    __syncthreads();
    wave_argmin(v, i);
    if ((tid & 63) == 0) { s_rv[tid >> 6] = v; s_ri[tid >> 6] = i; }
    __syncthreads();
    if (tid == 0) {
        float bv = s_rv[0]; int bi = s_ri[0];
        for (int w2 = 1; w2 < 4; w2++) {
            float ov = s_rv[w2]; int oi = s_ri[w2];
            if (ov < bv || (ov == bv && oi < bi)) { bv = ov; bi = oi; }
        }
        *slot = packvi(bv, bi);
    }
}

// Closed-form ring weight (Chebyshev ring + border-m=1 special)
__device__ inline float ring_weight(int px, int py, int kpx, int kpy, int bxc, int byc) {
    const int adx = abs(px - kpx);
    const int ady = abs(py - kpy);
    int M = 0;
    if (adx <= 15 && ady <= adx) M = adx;
    if (ady <= 15 && adx <= ady) M = max(M, ady);
    if ((px == bxc && ady <= 1) || (py == byc && adx <= 1)) M = max(M, 1);
    return (M > 0) ? fmaf(0.25f, (float)M, 0.5f) : BG_W;
}

// 4x bilinear upsample of stripe yg from s_wd (18 rows, L=1..16 own, 0/17 halo),
// stores 64 fine rows, returns per-thread fine argmin partial.
// thread = (suby = tid>>6, jx = tid&63).
__device__ inline VI upsample_stripe(const float* s_wd, int bn, int yg, int tid,
                                     float* out_x4) {
    const int jx   = tid & 63;
    const int suby = tid >> 6;
    const int jxm1 = max(jx - 1, 0);
    const int jxp1 = min(jx + 1, WW - 1);
    const bool xe0 = (jx == 0);
    const bool xe1 = (jx == WW - 1);

    auto xrow = [&](int L) -> float4 {
        const float* rr = s_wd + L * WW;
        const float a  = rr[jxm1];
        const float bb = rr[jx];
        const float c  = rr[jxp1];
        float4 o;
        o.x = xe0 ? bb : fmaf(0.375f, a, 0.625f * bb);
        o.y = xe0 ? bb : fmaf(0.125f, a, 0.875f * bb);
        o.z = xe1 ? bb : fmaf(0.125f, c, 0.875f * bb);
        o.w = xe1 ? bb : fmaf(0.375f, c, 0.625f * bb);
        return o;
    };
    auto lerp4 = [](float wa, const float4& A, float wb, const float4& B) {
        float4 o;
        o.x = fmaf(wa, A.x, wb * B.x);
        o.y = fmaf(wa, A.y, wb * B.y);
        o.z = fmaf(wa, A.z, wb * B.z);
        o.w = fmaf(wa, A.w, wb * B.w);
        return o;
    };

    VI fine = {FLT_MAX, 0x7fffffff};
    float4* xo4 = (float4*)(out_x4 + (size_t)bn * (256 * 256)) + jx;

    const int jy0 = yg * 16 + suby * 4;
    const int L0  = suby * 4 + 1;
    float4 Xc = xrow(L0);
    float4 Xp = xrow(L0 - 1);   // garbage iff jy0==0 (never used then)

    #pragma unroll
    for (int q = 0; q < 4; q++) {
        const int jy = jy0 + q;
        const int L  = L0 + q;
        const float4 Xn = xrow(L + 1);   // garbage iff jy==63 (never used then)
        float4 v0, v1, v2, v3;
        if (jy == 0) { v0 = Xc; v1 = Xc; }
        else {
            v0 = lerp4(0.375f, Xp, 0.625f, Xc);
            v1 = lerp4(0.125f, Xp, 0.875f, Xc);
        }
        if (jy == HH - 1) { v2 = Xc; v3 = Xc; }
        else {
            v2 = lerp4(0.875f, Xc, 0.125f, Xn);
            v3 = lerp4(0.625f, Xc, 0.375f, Xn);
        }
        const int r0 = jy * 4;
        xo4[(size_t)(r0 + 0) * 64] = v0;
        xo4[(size_t)(r0 + 1) * 64] = v1;
        xo4[(size_t)(r0 + 2) * 64] = v2;
        xo4[(size_t)(r0 + 3) * 64] = v3;
        const int ib = r0 * 256 + 4 * jx;
        VI a0 = row4min(v0, ib);
        VI a1 = row4min(v1, ib + 256);
        VI a2 = row4min(v2, ib + 512);
        VI a3 = row4min(v3, ib + 768);
        fine = vimin(fine, vimin(vimin(a0, a1), vimin(a2, a3)));
        Xp = Xc;
        Xc = Xn;
    }
    return fine;
}

// ---------------- Primary path: K1 map, K2 upsample ----------------

// K1: one block per bn. Full 64x64 wd map -> ws; coarse argmin -> parts[bn*8].
// Tiny LDS (no wd staging) -> occupancy limited only by VGPR.
__global__ __launch_bounds__(256) void ee_map(
    const float* __restrict__ kq,
    const float* __restrict__ mkeys,
    const int*   __restrict__ mjoints,
    float* __restrict__ wd_out,          // (BN, 4096)
    u64*   __restrict__ parts)           // stride 8, slot 0
{
    const int nb  = gridDim.x;
    const int bid = blockIdx.x;
    const int bn  = ((nb & 7) == 0) ? ((bid & 7) * (nb >> 3) + (bid >> 3)) : bid;
    const int b   = bn / NKEYS;
    const int tid = threadIdx.x;

    __shared__ float s_mk[CCH];
    __shared__ float s_rv[4];
    __shared__ int   s_ri[4];

    if (tid < CCH) s_mk[tid] = mkeys[bn * CCH + tid];
    __syncthreads();

    float k2 = 0.0f;
    #pragma unroll
    for (int c = 0; c < CCH; c++) { float v = s_mk[c]; k2 += v * v; }

    const int kpx = mjoints[bn * 2 + 0];
    const int kpy = mjoints[bn * 2 + 1];
    const int bxc = (kpx == 0) ? 0 : ((kpx == WW - 1) ? WW - 1 : -1);
    const int byc = (kpy == 0) ? 0 : ((kpy == HH - 1) ? HH - 1 : -1);

    const float4* kq4 = (const float4*)(kq + (size_t)b * CCH * HH * WW);
    float4* wd4 = (float4*)(wd_out + (size_t)bn * (HH * WW));

    VI best = {FLT_MAX, 0x7fffffff};

    for (int j = 0; j < 4; j++) {
        const int chunk = tid + (j << 8);   // 0..1023
        float4 dot = make_float4(0.f, 0.f, 0.f, 0.f);
        float4 q2  = make_float4(0.f, 0.f, 0.f, 0.f);
        #pragma unroll
        for (int c = 0; c < CCH; c++) {
            float4 v = kq4[c * 1024 + chunk];
            float  m = s_mk[c];
            dot.x += v.x * m;  dot.y += v.y * m;
            dot.z += v.z * m;  dot.w += v.w * m;
            q2.x  += v.x * v.x; q2.y += v.y * v.y;
            q2.z  += v.z * v.z; q2.w += v.w * v.w;
        }
        const int p0  = chunk * 4;
        const int py  = chunk >> 4;
        const int pxb = (chunk & 15) * 4;
        float4 w;
        w.x = sqrtf(fmaxf(q2.x + k2 - 2.0f * dot.x, 0.0f)) * ring_weight(pxb + 0, py, kpx, kpy, bxc, byc);
        w.y = sqrtf(fmaxf(q2.y + k2 - 2.0f * dot.y, 0.0f)) * ring_weight(pxb + 1, py, kpx, kpy, bxc, byc);
        w.z = sqrtf(fmaxf(q2.z + k2 - 2.0f * dot.z, 0.0f)) * ring_weight(pxb + 2, py, kpx, kpy, bxc, byc);
        w.w = sqrtf(fmaxf(q2.w + k2 - 2.0f * dot.w, 0.0f)) * ring_weight(pxb + 3, py, kpx, kpy, bxc, byc);
        wd4[chunk] = w;
        best = vimin(best, row4min(w, p0));   // p ascending per thread
    }

    block_argmin_slot(best.v, best.i, tid, s_rv, s_ri, &parts[(size_t)bn * 8]);
}

// K2: one block per (bn, stripe). Stage 18 wd rows -> LDS, upsample, fine argmin.
__global__ __launch_bounds__(256) void ee_up(
    const float* __restrict__ wd_in,     // (BN, 4096)
    float* __restrict__ out_x4,
    u64*   __restrict__ parts)           // stride 8, slots 4..7
{
    const int nb  = gridDim.x;
    const int bid = blockIdx.x;
    const int bnyg = ((nb & 7) == 0) ? ((bid & 7) * (nb >> 3) + (bid >> 3)) : bid;
    const int bn  = bnyg >> 2;
    const int yg  = bnyg & 3;
    const int tid = threadIdx.x;

    __shared__ __align__(16) float s_wd[18 * WW];
    __shared__ float s_rv[4];
    __shared__ int   s_ri[4];

    const float4* wsrc = (const float4*)(wd_in + (size_t)bn * (HH * WW));
    const int gy_base = yg * 16 - 1;
    #pragma unroll
    for (int pass = 0; pass < 2; pass++) {
        const int chunk = tid + (pass << 8);
        if (chunk < 288) {
            const int L  = chunk >> 4;
            const int cx = chunk & 15;
            const int gy = gy_base + L;
            if ((unsigned)gy < (unsigned)HH)
                ((float4*)s_wd)[chunk] = wsrc[gy * 16 + cx];
        }
    }
    __syncthreads();

    VI fine = upsample_stripe(s_wd, bn, yg, tid, out_x4);
    block_argmin_slot(fine.v, fine.i, tid, s_rv, s_ri, &parts[(size_t)bn * 8 + 4 + yg]);
}

// ---------------- Fallback path: merged (round-2, known good) ----------------

__global__ __launch_bounds__(256) void ee_merged(
    const float* __restrict__ kq,
    const float* __restrict__ mkeys,
    const int*   __restrict__ mjoints,
    float* __restrict__ out_x4,
    u64* parts)                          // stride 16: slots yg (coarse), 4+yg (fine)
{
    const int nb  = gridDim.x;
    const int bid = blockIdx.x;
    const int bnyg = ((nb & 7) == 0) ? ((bid & 7) * (nb >> 3) + (bid >> 3)) : bid;
    const int bn  = bnyg >> 2;
    const int yg  = bnyg & 3;
    const int b   = bn / NKEYS;
    const int tid = threadIdx.x;

    __shared__ float s_mk[CCH];
    __shared__ __align__(16) float s_wd[18 * WW];
    __shared__ float s_rv[4];
    __shared__ int   s_ri[4];

    if (tid < CCH) s_mk[tid] = mkeys[bn * CCH + tid];
    __syncthreads();

    float k2 = 0.0f;
    #pragma unroll
    for (int c = 0; c < CCH; c++) { float v = s_mk[c]; k2 += v * v; }

    const int kpx = mjoints[bn * 2 + 0];
    const int kpy = mjoints[bn * 2 + 1];
    const int bxc = (kpx == 0) ? 0 : ((kpx == WW - 1) ? WW - 1 : -1);
    const int byc = (kpy == 0) ? 0 : ((kpy == HH - 1) ? HH - 1 : -1);

    const float4* kq4 = (const float4*)(kq + (size_t)b * CCH * HH * WW);

    VI coarse = {FLT_MAX, 0x7fffffff};
    const int gy_base = yg * 16 - 1;

    #pragma unroll
    for (int pass = 0; pass < 2; pass++) {
        const int chunk = tid + (pass << 8);
        if (chunk < 288) {
            const int L  = chunk >> 4;
            const int cx = chunk & 15;
            const int gy = gy_base + L;
            if ((unsigned)gy < (unsigned)HH) {
                const int gchunk = gy * 16 + cx;
                float4 dot = make_float4(0.f, 0.f, 0.f, 0.f);
                float4 q2  = make_float4(0.f, 0.f, 0.f, 0.f);
                #pragma unroll
                for (int c = 0; c < CCH; c++) {
                    float4 v = kq4[c * 1024 + gchunk];
                    float  m = s_mk[c];
                    dot.x += v.x * m;  dot.y += v.y * m;
                    dot.z += v.z * m;  dot.w += v.w * m;
                    q2.x  += v.x * v.x; q2.y += v.y * v.y;
                    q2.z  += v.z * v.z; q2.w += v.w * v.w;
                }
                const int pxb = cx * 4;
                float4 w;
                w.x = sqrtf(fmaxf(q2.x + k2 - 2.0f * dot.x, 0.0f)) * ring_weight(pxb + 0, gy, kpx, kpy, bxc, byc);
                w.y = sqrtf(fmaxf(q2.y + k2 - 2.0f * dot.y, 0.0f)) * ring_weight(pxb + 1, gy, kpx, kpy, bxc, byc);
                w.z = sqrtf(fmaxf(q2.z + k2 - 2.0f * dot.z, 0.0f)) * ring_weight(pxb + 2, gy, kpx, kpy, bxc, byc);
                w.w = sqrtf(fmaxf(q2.w + k2 - 2.0f * dot.w, 0.0f)) * ring_weight(pxb + 3, gy, kpx, kpy, bxc, byc);
                ((float4*)s_wd)[chunk] = w;
                if (L >= 1 && L <= 16)
                    coarse = vimin(coarse, row4min(w, gy * WW + pxb));
            }
        }
    }

    block_argmin_slot(coarse.v, coarse.i, tid, s_rv, s_ri, &parts[(size_t)bn * 16 + yg]);
    __syncthreads();   // s_wd fully staged for all waves (also ensured above)

    VI fine = upsample_stripe(s_wd, bn, yg, tid, out_x4);
    block_argmin_slot(fine.v, fine.i, tid, s_rv, s_ri, &parts[(size_t)bn * 16 + 4 + yg]);
}

// ---------------- Finalize ----------------
// NOTE: no __restrict__ on aliasable pointers (fallback stores parts inside out_keys).
__global__ __launch_bounds__(64) void ee_fin(
    const float* kq,
    const float* mkeys,
    float* out_joints,
    float* out_valid,
    float* out_keys,
    const u64* parts, int pstride, int c_cnt)
{
    const int bn   = blockIdx.x;
    const int b    = bn / NKEYS;
    const int lane = threadIdx.x;

    u64 pc = (lane < c_cnt) ? parts[(size_t)bn * pstride + lane]     : ~0ull;
    u64 pf = (lane < 4)     ? parts[(size_t)bn * pstride + 4 + lane] : ~0ull;
    #pragma unroll
    for (int off = 1; off <= 2; off <<= 1) {
        u64 o;
        o = __shfl_xor(pc, off, 64); if (o < pc) pc = o;
        o = __shfl_xor(pf, off, 64); if (o < pf) pf = o;
    }
    pc = __shfl(pc, 0, 64);
    pf = __shfl(pf, 0, 64);

    const float min_d = __uint_as_float((unsigned int)(pc >> 32));
    const int   cbest = (int)(pc & 0xffffffffu);

    const float mv = (lane < CCH) ? mkeys[(size_t)bn * CCH + lane] : 0.0f;
    const bool  nz = __any(mv != 0.0f);
    const bool  valid = nz && ((int)floorf(min_d) <= 5);

    float o = mv;
    if (lane < CCH && valid)
        o = kq[(size_t)(b * CCH + lane) * (HH * WW) + cbest];

    __syncthreads();   // drain all loads before (possibly aliasing) stores

    if (lane < CCH) out_keys[(size_t)bn * CCH + lane] = o;
    if (lane == 0) {
        const int fi = (int)(pf & 0xffffffffu);
        out_joints[bn * 2 + 0] = (float)(valid ? (fi >> 8)  : -1);
        out_joints[bn * 2 + 1] = (float)(valid ? (fi & 255) : -1);
        out_valid[bn] = valid ? 1.0f : 0.0f;
    }
}

extern "C" void kernel_launch(void* const* d_in, const int* in_sizes, int n_in,
                              void* d_out, int out_size, void* d_ws, size_t ws_size,
                              hipStream_t stream) {
    const float* kq = (const float*)d_in[0];
    const float* mk = (const float*)d_in[1];
    const int*   mj = (const int*)d_in[2];

    const int B  = in_sizes[1] / (NKEYS * CCH);   // 64
    const int BN = B * NKEYS;                     // 1088

    float* out_f     = (float*)d_out;
    float* o_joints  = out_f;                     // B*N*2
    float* o_valid   = o_joints + BN * 2;         // B*N
    float* o_keys    = o_valid + BN;              // B*N*C
    float* o_x4      = o_keys + BN * CCH;         // B*N*256*256

    const size_t wd_bytes = (size_t)BN * (HH * WW) * sizeof(float);
    const size_t need     = wd_bytes + (size_t)BN * 8 * sizeof(u64);

    if (ws_size >= need) {
        // Primary: split pipeline through workspace.
        float* wd   = (float*)d_ws;
        u64*  parts = (u64*)((char*)d_ws + wd_bytes);   // BN * 8 slots
        ee_map<<<dim3(BN),     dim3(256), 0, stream>>>(kq, mk, mj, wd, parts);
        ee_up <<<dim3(BN * 4), dim3(256), 0, stream>>>(wd, o_x4, parts);
        ee_fin<<<dim3(BN),     dim3(64),  0, stream>>>(kq, mk, o_joints, o_valid, o_keys,
                                                       parts, 8, 1);
    } else {
        // Fallback: merged kernel; partials live in each bn's own out_keys slot
        // (16 u64 = 128 B per bn, read by fin before it overwrites -- self-owned,
        // fenced by __syncthreads inside fin).
        u64* parts = (u64*)o_keys;
        ee_merged<<<dim3(BN * 4), dim3(256), 0, stream>>>(kq, mk, mj, o_x4, parts);
        ee_fin   <<<dim3(BN),     dim3(64),  0, stream>>>(kq, mk, o_joints, o_valid, o_keys,
                                                          parts, 16, 4);
    }
}

// Round 5
// 356.145 us; speedup vs baseline: 1.1429x; 1.1429x over previous
//
#include <hip/hip_runtime.h>
#include <cfloat>

#define HH 64
#define WW 64
#define NKEYS 17
#define CCH 32
#define BG_W 10.0f

typedef unsigned long long u64;
typedef float f32x4 __attribute__((ext_vector_type(4)));

__device__ inline void nt_store4(const float4& v, float4* p) {
    __builtin_nontemporal_store(*(const f32x4*)&v, (f32x4*)p);
}

struct VI { float v; int i; };
// strict <: keeps left on ties. Call with left = lower index.
__device__ inline VI vimin(VI a, VI b) { return (b.v < a.v) ? b : a; }

__device__ inline VI row4min(const float4& v, int i0) {
    VI a = {v.x, i0}, b = {v.y, i0 + 1}, c = {v.z, i0 + 2}, d = {v.w, i0 + 3};
    return vimin(vimin(a, b), vimin(c, d));
}

__device__ inline void wave_argmin(float &v, int &i) {
    #pragma unroll
    for (int off = 32; off > 0; off >>= 1) {
        float ov = __shfl_down(v, off, 64);
        int   oi = __shfl_down(i, off, 64);
        if (ov < v || (ov == v && oi < i)) { v = ov; i = oi; }
    }
}

__device__ inline u64 packvi(float v, int i) {
    // wdist >= 0 so float bits are monotone: u64 order == (value, index) lex order
    return ((u64)__float_as_uint(v) << 32) | (unsigned int)i;
}

// block argmin -> *slot. Leading barrier protects s_rv/s_ri reuse and orders
// prior LDS writes before later reads.
__device__ inline void block_argmin_slot(float v, int i, int tid,
                                         float* s_rv, int* s_ri, u64* slot) {
    __syncthreads();
    wave_argmin(v, i);
    if ((tid & 63) == 0) { s_rv[tid >> 6] = v; s_ri[tid >> 6] = i; }
    __syncthreads();
    if (tid == 0) {
        float bv = s_rv[0]; int bi = s_ri[0];
        for (int w2 = 1; w2 < 4; w2++) {
            float ov = s_rv[w2]; int oi = s_ri[w2];
            if (ov < bv || (ov == bv && oi < bi)) { bv = ov; bi = oi; }
        }
        *slot = packvi(bv, bi);
    }
}

// Closed-form ring weight (Chebyshev ring + border-m=1 special)
__device__ inline float ring_weight(int px, int py, int kpx, int kpy, int bxc, int byc) {
    const int adx = abs(px - kpx);
    const int ady = abs(py - kpy);
    int M = 0;
    if (adx <= 15 && ady <= adx) M = adx;
    if (ady <= 15 && adx <= ady) M = max(M, ady);
    if ((px == bxc && ady <= 1) || (py == byc && adx <= 1)) M = max(M, 1);
    return (M > 0) ? fmaf(0.25f, (float)M, 0.5f) : BG_W;
}

// 4x bilinear upsample of stripe yg from s_wd (18 rows, L=1..16 own, 0/17 halo),
// nontemporal stores of 64 fine rows, returns per-thread fine argmin partial.
// thread = (suby = tid>>6, jx = tid&63).
__device__ inline VI upsample_stripe(const float* s_wd, int bn, int yg, int tid,
                                     float* out_x4) {
    const int jx   = tid & 63;
    const int suby = tid >> 6;
    const int jxm1 = max(jx - 1, 0);
    const int jxp1 = min(jx + 1, WW - 1);
    const bool xe0 = (jx == 0);
    const bool xe1 = (jx == WW - 1);

    auto xrow = [&](int L) -> float4 {
        const float* rr = s_wd + L * WW;
        const float a  = rr[jxm1];
        const float bb = rr[jx];
        const float c  = rr[jxp1];
        float4 o;
        o.x = xe0 ? bb : fmaf(0.375f, a, 0.625f * bb);
        o.y = xe0 ? bb : fmaf(0.125f, a, 0.875f * bb);
        o.z = xe1 ? bb : fmaf(0.125f, c, 0.875f * bb);
        o.w = xe1 ? bb : fmaf(0.375f, c, 0.625f * bb);
        return o;
    };
    auto lerp4 = [](float wa, const float4& A, float wb, const float4& B) {
        float4 o;
        o.x = fmaf(wa, A.x, wb * B.x);
        o.y = fmaf(wa, A.y, wb * B.y);
        o.z = fmaf(wa, A.z, wb * B.z);
        o.w = fmaf(wa, A.w, wb * B.w);
        return o;
    };

    VI fine = {FLT_MAX, 0x7fffffff};
    float4* xo4 = (float4*)(out_x4 + (size_t)bn * (256 * 256)) + jx;

    const int jy0 = yg * 16 + suby * 4;
    const int L0  = suby * 4 + 1;
    float4 Xc = xrow(L0);
    float4 Xp = xrow(L0 - 1);   // garbage iff jy0==0 (never used then)

    #pragma unroll
    for (int q = 0; q < 4; q++) {
        const int jy = jy0 + q;
        const int L  = L0 + q;
        const float4 Xn = xrow(L + 1);   // garbage iff jy==63 (never used then)
        float4 v0, v1, v2, v3;
        if (jy == 0) { v0 = Xc; v1 = Xc; }
        else {
            v0 = lerp4(0.375f, Xp, 0.625f, Xc);
            v1 = lerp4(0.125f, Xp, 0.875f, Xc);
        }
        if (jy == HH - 1) { v2 = Xc; v3 = Xc; }
        else {
            v2 = lerp4(0.875f, Xc, 0.125f, Xn);
            v3 = lerp4(0.625f, Xc, 0.375f, Xn);
        }
        const int r0 = jy * 4;
        nt_store4(v0, &xo4[(size_t)(r0 + 0) * 64]);
        nt_store4(v1, &xo4[(size_t)(r0 + 1) * 64]);
        nt_store4(v2, &xo4[(size_t)(r0 + 2) * 64]);
        nt_store4(v3, &xo4[(size_t)(r0 + 3) * 64]);
        const int ib = r0 * 256 + 4 * jx;
        VI a0 = row4min(v0, ib);
        VI a1 = row4min(v1, ib + 256);
        VI a2 = row4min(v2, ib + 512);
        VI a3 = row4min(v3, ib + 768);
        fine = vimin(fine, vimin(vimin(a0, a1), vimin(a2, a3)));
        Xp = Xc;
        Xc = Xn;
    }
    return fine;
}

// b-major kernel: one block per (b, y-stripe). Grid = B*4 = 256 = 1 block/CU.
// Own 16 coarse rows held as kq in registers (32 float4/thread); loop n=0..16
// computing the wd stripe + upsample + argmin partials per key. Halo rows
// (2 per stripe) streamed per-n by 8 lanes/wave (L1-resident after n=0).
__global__ __launch_bounds__(256, 1) void ee_bmajor(
    const float* __restrict__ kq,      // (B, C, H, W)
    const float* __restrict__ mkeys,   // (B, N, C)
    const int*   __restrict__ mjoints, // (B, N, 2)
    float* __restrict__ out_x4,        // (B, N, 256, 256)
    u64*   __restrict__ parts)         // stride 16: yg (coarse), 4+yg (fine)
{
    const int bid = blockIdx.x;
    const int b   = bid >> 2;
    const int yg  = bid & 3;
    const int tid = threadIdx.x;
    const int lane = tid & 63;
    const int wv   = tid >> 6;

    __shared__ __align__(16) float s_mk[NKEYS * CCH];
    __shared__ float s_k2[NKEYS];
    __shared__ int   s_mj[NKEYS * 2];
    __shared__ __align__(16) float s_wd[18 * WW];
    __shared__ float s_rv[4];
    __shared__ int   s_ri[4];

    // ---- stage per-b key data ----
    {
        const float* mkb = mkeys + (size_t)b * NKEYS * CCH;
        for (int t = tid; t < NKEYS * CCH; t += 256) s_mk[t] = mkb[t];
        if (tid < NKEYS * 2) s_mj[tid] = mjoints[b * NKEYS * 2 + tid];
    }
    __syncthreads();
    if (tid < NKEYS) {
        float s = 0.0f;
        #pragma unroll
        for (int c = 0; c < CCH; c++) { float v = s_mk[tid * CCH + c]; s = fmaf(v, v, s); }
        s_k2[tid] = s;
    }

    // ---- own chunk -> registers (statically indexed; 1 wave/SIMD budget) ----
    const int r   = tid >> 4;             // own coarse row 0..15
    const int cx  = tid & 15;             // float4-chunk col
    const int gy  = yg * 16 + r;          // global coarse row
    const int px0 = cx * 4;
    const float4* kq4 = (const float4*)(kq + (size_t)b * CCH * HH * WW);
    const int mychunk = gy * 16 + cx;

    float4 kqr[CCH];
    #pragma unroll
    for (int c = 0; c < CCH; c++) kqr[c] = kq4[c * 1024 + mychunk];

    float4 q2 = make_float4(0.f, 0.f, 0.f, 0.f);
    #pragma unroll
    for (int c = 0; c < CCH; c++) {
        const float4 v = kqr[c];
        q2.x = fmaf(v.x, v.x, q2.x); q2.y = fmaf(v.y, v.y, q2.y);
        q2.z = fmaf(v.z, v.z, q2.z); q2.w = fmaf(v.w, v.w, q2.w);
    }

    // ---- halo assignment: lanes 0..7 of each wave -> halo chunk wv*8+lane ----
    const int  hh      = wv * 8 + lane;               // 0..31 when lane<8
    const bool ishalo  = (lane < 8);
    const int  hL      = (hh < 16) ? 0 : 17;
    const int  hcx     = (hh < 16) ? hh : hh - 16;
    const int  hgy     = (hh < 16) ? (yg * 16 - 1) : (yg * 16 + 16);
    const bool halo_act = ishalo && ((unsigned)hgy < (unsigned)HH);
    const int  hchunk  = hgy * 16 + hcx;

    __syncthreads();   // s_k2 ready

    for (int n = 0; n < NKEYS; n++) {
        const int bn  = b * NKEYS + n;
        const float k2 = s_k2[n];
        const int kpx = s_mj[n * 2 + 0];
        const int kpy = s_mj[n * 2 + 1];
        const int bxc = (kpx == 0) ? 0 : ((kpx == WW - 1) ? WW - 1 : -1);
        const int byc = (kpy == 0) ? 0 : ((kpy == HH - 1) ? HH - 1 : -1);

        // own wd from registers
        float4 dot = make_float4(0.f, 0.f, 0.f, 0.f);
        #pragma unroll
        for (int i = 0; i < 8; i++) {
            const float4 m4 = ((const float4*)s_mk)[n * 8 + i];
            const float mk[4] = {m4.x, m4.y, m4.z, m4.w};
            #pragma unroll
            for (int j = 0; j < 4; j++) {
                const float4 v = kqr[i * 4 + j];
                dot.x = fmaf(v.x, mk[j], dot.x);
                dot.y = fmaf(v.y, mk[j], dot.y);
                dot.z = fmaf(v.z, mk[j], dot.z);
                dot.w = fmaf(v.w, mk[j], dot.w);
            }
        }
        float4 w;
        w.x = sqrtf(fmaxf(q2.x + k2 - 2.0f * dot.x, 0.0f)) * ring_weight(px0 + 0, gy, kpx, kpy, bxc, byc);
        w.y = sqrtf(fmaxf(q2.y + k2 - 2.0f * dot.y, 0.0f)) * ring_weight(px0 + 1, gy, kpx, kpy, bxc, byc);
        w.z = sqrtf(fmaxf(q2.z + k2 - 2.0f * dot.z, 0.0f)) * ring_weight(px0 + 2, gy, kpx, kpy, bxc, byc);
        w.w = sqrtf(fmaxf(q2.w + k2 - 2.0f * dot.w, 0.0f)) * ring_weight(px0 + 3, gy, kpx, kpy, bxc, byc);
        ((float4*)s_wd)[(r + 1) * 16 + cx] = w;
        VI coarse = row4min(w, gy * WW + px0);    // ascending p within thread & tid

        // halo wd (streamed; 16KB stays in L1 across n)
        if (halo_act) {
            float4 hd = make_float4(0.f, 0.f, 0.f, 0.f);
            float4 hq = make_float4(0.f, 0.f, 0.f, 0.f);
            #pragma unroll
            for (int i = 0; i < 8; i++) {
                const float4 m4 = ((const float4*)s_mk)[n * 8 + i];
                const float mk[4] = {m4.x, m4.y, m4.z, m4.w};
                #pragma unroll
                for (int j = 0; j < 4; j++) {
                    const float4 v = kq4[(i * 4 + j) * 1024 + hchunk];
                    hd.x = fmaf(v.x, mk[j], hd.x); hd.y = fmaf(v.y, mk[j], hd.y);
                    hd.z = fmaf(v.z, mk[j], hd.z); hd.w = fmaf(v.w, mk[j], hd.w);
                    hq.x = fmaf(v.x, v.x, hq.x);   hq.y = fmaf(v.y, v.y, hq.y);
                    hq.z = fmaf(v.z, v.z, hq.z);   hq.w = fmaf(v.w, v.w, hq.w);
                }
            }
            const int hx0 = hcx * 4;
            float4 hw;
            hw.x = sqrtf(fmaxf(hq.x + k2 - 2.0f * hd.x, 0.0f)) * ring_weight(hx0 + 0, hgy, kpx, kpy, bxc, byc);
            hw.y = sqrtf(fmaxf(hq.y + k2 - 2.0f * hd.y, 0.0f)) * ring_weight(hx0 + 1, hgy, kpx, kpy, bxc, byc);
            hw.z = sqrtf(fmaxf(hq.z + k2 - 2.0f * hd.z, 0.0f)) * ring_weight(hx0 + 2, hgy, kpx, kpy, bxc, byc);
            hw.w = sqrtf(fmaxf(hq.w + k2 - 2.0f * hd.w, 0.0f)) * ring_weight(hx0 + 3, hgy, kpx, kpy, bxc, byc);
            ((float4*)s_wd)[hL * 16 + hcx] = hw;
        }

        // coarse partial (its leading barrier also publishes s_wd for upsample)
        block_argmin_slot(coarse.v, coarse.i, tid, s_rv, s_ri,
                          &parts[(size_t)bn * 16 + yg]);

        VI fine = upsample_stripe(s_wd, bn, yg, tid, out_x4);
        // fine partial (its leading barrier also protects s_wd before next n)
        block_argmin_slot(fine.v, fine.i, tid, s_rv, s_ri,
                          &parts[(size_t)bn * 16 + 4 + yg]);
    }
}

// ---------------- Finalize ----------------
// NOTE: no __restrict__ (parts may alias the out_keys region when d_ws is small).
__global__ __launch_bounds__(64) void ee_fin(
    const float* kq,
    const float* mkeys,
    float* out_joints,
    float* out_valid,
    float* out_keys,
    const u64* parts)
{
    const int bn   = blockIdx.x;
    const int b    = bn / NKEYS;
    const int lane = threadIdx.x;

    u64 pc = (lane < 4) ? parts[(size_t)bn * 16 + lane]     : ~0ull;
    u64 pf = (lane < 4) ? parts[(size_t)bn * 16 + 4 + lane] : ~0ull;
    #pragma unroll
    for (int off = 1; off <= 2; off <<= 1) {
        u64 o;
        o = __shfl_xor(pc, off, 64); if (o < pc) pc = o;
        o = __shfl_xor(pf, off, 64); if (o < pf) pf = o;
    }
    pc = __shfl(pc, 0, 64);
    pf = __shfl(pf, 0, 64);

    const float min_d = __uint_as_float((unsigned int)(pc >> 32));
    const int   cbest = (int)(pc & 0xffffffffu);

    const float mv = (lane < CCH) ? mkeys[(size_t)bn * CCH + lane] : 0.0f;
    const bool  nz = __any(mv != 0.0f);
    const bool  valid = nz && ((int)floorf(min_d) <= 5);

    float o = mv;
    if (lane < CCH && valid)
        o = kq[(size_t)(b * CCH + lane) * (HH * WW) + cbest];

    __syncthreads();   // drain loads before (possibly aliasing) stores

    if (lane < CCH) out_keys[(size_t)bn * CCH + lane] = o;
    if (lane == 0) {
        const int fi = (int)(pf & 0xffffffffu);
        out_joints[bn * 2 + 0] = (float)(valid ? (fi >> 8)  : -1);
        out_joints[bn * 2 + 1] = (float)(valid ? (fi & 255) : -1);
        out_valid[bn] = valid ? 1.0f : 0.0f;
    }
}

extern "C" void kernel_launch(void* const* d_in, const int* in_sizes, int n_in,
                              void* d_out, int out_size, void* d_ws, size_t ws_size,
                              hipStream_t stream) {
    const float* kq = (const float*)d_in[0];
    const float* mk = (const float*)d_in[1];
    const int*   mj = (const int*)d_in[2];

    const int B  = in_sizes[1] / (NKEYS * CCH);   // 64
    const int BN = B * NKEYS;                     // 1088

    float* out_f     = (float*)d_out;
    float* o_joints  = out_f;                     // B*N*2
    float* o_valid   = o_joints + BN * 2;         // B*N
    float* o_keys    = o_valid + BN;              // B*N*C
    float* o_x4      = o_keys + BN * CCH;         // B*N*256*256

    // Partials: BN*16 u64. Prefer d_ws; else stash in each bn's own out_keys
    // slot (BN*16 u64 == BN*32 floats == out_keys size exactly); ee_fin reads
    // its own slot before overwriting.
    u64* parts;
    if (ws_size >= (size_t)BN * 16 * sizeof(u64)) parts = (u64*)d_ws;
    else                                          parts = (u64*)o_keys;

    ee_bmajor<<<dim3(B * 4), dim3(256), 0, stream>>>(kq, mk, mj, o_x4, parts);
    ee_fin   <<<dim3(BN),    dim3(64),  0, stream>>>(kq, mk, o_joints, o_valid, o_keys, parts);
}

// Round 6
// 344.986 us; speedup vs baseline: 1.1799x; 1.0323x over previous
//
#include <hip/hip_runtime.h>
#include <cfloat>

#define HH 64
#define WW 64
#define NKEYS 17
#define CCH 32
#define BG_W 10.0f

typedef unsigned long long u64;
typedef float f32x4 __attribute__((ext_vector_type(4)));

__device__ inline void nt_store4(const float4& v, float4* p) {
    __builtin_nontemporal_store(*(const f32x4*)&v, (f32x4*)p);
}

struct VI { float v; int i; };
// strict <: keeps left on ties. Call with left = lower index.
__device__ inline VI vimin(VI a, VI b) { return (b.v < a.v) ? b : a; }

__device__ inline VI row4min(const float4& v, int i0) {
    VI a = {v.x, i0}, b = {v.y, i0 + 1}, c = {v.z, i0 + 2}, d = {v.w, i0 + 3};
    return vimin(vimin(a, b), vimin(c, d));
}

// shuffle-only wave argmin (no LDS, no barrier); ties -> lower index
__device__ inline void wave_argmin(float &v, int &i) {
    #pragma unroll
    for (int off = 32; off > 0; off >>= 1) {
        float ov = __shfl_down(v, off, 64);
        int   oi = __shfl_down(i, off, 64);
        if (ov < v || (ov == v && oi < i)) { v = ov; i = oi; }
    }
}

__device__ inline u64 packvi(float v, int i) {
    // wdist >= 0 so float bits are monotone: u64 order == (value, index) lex order
    return ((u64)__float_as_uint(v) << 32) | (unsigned int)i;
}

// block argmin -> *slot (fallback path only; costs 2 barriers)
__device__ inline void block_argmin_slot(float v, int i, int tid,
                                         float* s_rv, int* s_ri, u64* slot) {
    __syncthreads();
    wave_argmin(v, i);
    if ((tid & 63) == 0) { s_rv[tid >> 6] = v; s_ri[tid >> 6] = i; }
    __syncthreads();
    if (tid == 0) {
        float bv = s_rv[0]; int bi = s_ri[0];
        for (int w2 = 1; w2 < 4; w2++) {
            float ov = s_rv[w2]; int oi = s_ri[w2];
            if (ov < bv || (ov == bv && oi < bi)) { bv = ov; bi = oi; }
        }
        *slot = packvi(bv, bi);
    }
}

// Closed-form ring weight (Chebyshev ring + border-m=1 special)
__device__ inline float ring_weight(int px, int py, int kpx, int kpy, int bxc, int byc) {
    const int adx = abs(px - kpx);
    const int ady = abs(py - kpy);
    int M = 0;
    if (adx <= 15 && ady <= adx) M = adx;
    if (ady <= 15 && adx <= ady) M = max(M, ady);
    if ((px == bxc && ady <= 1) || (py == byc && adx <= 1)) M = max(M, 1);
    return (M > 0) ? fmaf(0.25f, (float)M, 0.5f) : BG_W;
}

// 4x bilinear upsample of stripe yg from s_wd (18 rows, L=1..16 own, 0/17 halo),
// nontemporal stores of 64 fine rows, returns per-thread fine argmin partial.
// thread = (suby = tid>>6, jx = tid&63).
__device__ inline VI upsample_stripe(const float* s_wd, int bn, int yg, int tid,
                                     float* out_x4) {
    const int jx   = tid & 63;
    const int suby = tid >> 6;
    const int jxm1 = max(jx - 1, 0);
    const int jxp1 = min(jx + 1, WW - 1);
    const bool xe0 = (jx == 0);
    const bool xe1 = (jx == WW - 1);

    auto xrow = [&](int L) -> float4 {
        const float* rr = s_wd + L * WW;
        const float a  = rr[jxm1];
        const float bb = rr[jx];
        const float c  = rr[jxp1];
        float4 o;
        o.x = xe0 ? bb : fmaf(0.375f, a, 0.625f * bb);
        o.y = xe0 ? bb : fmaf(0.125f, a, 0.875f * bb);
        o.z = xe1 ? bb : fmaf(0.125f, c, 0.875f * bb);
        o.w = xe1 ? bb : fmaf(0.375f, c, 0.625f * bb);
        return o;
    };
    auto lerp4 = [](float wa, const float4& A, float wb, const float4& B) {
        float4 o;
        o.x = fmaf(wa, A.x, wb * B.x);
        o.y = fmaf(wa, A.y, wb * B.y);
        o.z = fmaf(wa, A.z, wb * B.z);
        o.w = fmaf(wa, A.w, wb * B.w);
        return o;
    };

    VI fine = {FLT_MAX, 0x7fffffff};
    float4* xo4 = (float4*)(out_x4 + (size_t)bn * (256 * 256)) + jx;

    const int jy0 = yg * 16 + suby * 4;
    const int L0  = suby * 4 + 1;
    float4 Xc = xrow(L0);
    float4 Xp = xrow(L0 - 1);   // garbage iff jy0==0 (never used then)

    #pragma unroll
    for (int q = 0; q < 4; q++) {
        const int jy = jy0 + q;
        const int L  = L0 + q;
        const float4 Xn = xrow(L + 1);   // garbage iff jy==63 (never used then)
        float4 v0, v1, v2, v3;
        if (jy == 0) { v0 = Xc; v1 = Xc; }
        else {
            v0 = lerp4(0.375f, Xp, 0.625f, Xc);
            v1 = lerp4(0.125f, Xp, 0.875f, Xc);
        }
        if (jy == HH - 1) { v2 = Xc; v3 = Xc; }
        else {
            v2 = lerp4(0.875f, Xc, 0.125f, Xn);
            v3 = lerp4(0.625f, Xc, 0.375f, Xn);
        }
        const int r0 = jy * 4;
        nt_store4(v0, &xo4[(size_t)(r0 + 0) * 64]);
        nt_store4(v1, &xo4[(size_t)(r0 + 1) * 64]);
        nt_store4(v2, &xo4[(size_t)(r0 + 2) * 64]);
        nt_store4(v3, &xo4[(size_t)(r0 + 3) * 64]);
        const int ib = r0 * 256 + 4 * jx;
        VI a0 = row4min(v0, ib);
        VI a1 = row4min(v1, ib + 256);
        VI a2 = row4min(v2, ib + 512);
        VI a3 = row4min(v3, ib + 768);
        fine = vimin(fine, vimin(vimin(a0, a1), vimin(a2, a3)));
        Xp = Xc;
        Xc = Xn;
    }
    return fine;
}

// Merged kernel, one block per (bn, y-stripe).
// WP=true : wave-level argmin partials, ZERO reduction barriers; parts stride 32
//           (coarse slots 0..15 = yg*4+wave, fine slots 16..31). Blocks retire
//           with nt-stores in flight -> store drain overlaps next block's compute.
// WP=false: fallback (round-2 structure, block-level partials, stride 16, fits
//           in the out_keys region when d_ws is too small).
template<bool WP>
__global__ __launch_bounds__(256) void ee_merged(
    const float* __restrict__ kq,
    const float* __restrict__ mkeys,
    const int*   __restrict__ mjoints,
    float* __restrict__ out_x4,
    u64* parts)
{
    const int nb  = gridDim.x;
    const int bid = blockIdx.x;
    const int bnyg = ((nb & 7) == 0) ? ((bid & 7) * (nb >> 3) + (bid >> 3)) : bid;
    const int bn  = bnyg >> 2;
    const int yg  = bnyg & 3;
    const int b   = bn / NKEYS;
    const int tid = threadIdx.x;
    const int wv  = tid >> 6;

    __shared__ float s_mk[CCH];
    __shared__ __align__(16) float s_wd[18 * WW];
    __shared__ float s_rv[4];
    __shared__ int   s_ri[4];

    if (tid < CCH) s_mk[tid] = mkeys[bn * CCH + tid];
    __syncthreads();   // only mkeys loads in flight: cheap drain

    float k2 = 0.0f;
    #pragma unroll
    for (int c = 0; c < CCH; c++) { float v = s_mk[c]; k2 += v * v; }

    const int kpx = mjoints[bn * 2 + 0];
    const int kpy = mjoints[bn * 2 + 1];
    const int bxc = (kpx == 0) ? 0 : ((kpx == WW - 1) ? WW - 1 : -1);
    const int byc = (kpy == 0) ? 0 : ((kpy == HH - 1) ? HH - 1 : -1);

    const float4* kq4 = (const float4*)(kq + (size_t)b * CCH * HH * WW);

    VI coarse = {FLT_MAX, 0x7fffffff};
    const int gy_base = yg * 16 - 1;

    #pragma unroll
    for (int pass = 0; pass < 2; pass++) {
        const int chunk = tid + (pass << 8);
        if (chunk < 288) {
            const int L  = chunk >> 4;
            const int cx = chunk & 15;
            const int gy = gy_base + L;
            if ((unsigned)gy < (unsigned)HH) {
                const int gchunk = gy * 16 + cx;
                float4 dot = make_float4(0.f, 0.f, 0.f, 0.f);
                float4 q2  = make_float4(0.f, 0.f, 0.f, 0.f);
                #pragma unroll
                for (int c = 0; c < CCH; c++) {
                    float4 v = kq4[c * 1024 + gchunk];
                    float  m = s_mk[c];
                    dot.x += v.x * m;  dot.y += v.y * m;
                    dot.z += v.z * m;  dot.w += v.w * m;
                    q2.x  += v.x * v.x; q2.y += v.y * v.y;
                    q2.z  += v.z * v.z; q2.w += v.w * v.w;
                }
                const int pxb = cx * 4;
                float4 w;
                w.x = sqrtf(fmaxf(q2.x + k2 - 2.0f * dot.x, 0.0f)) * ring_weight(pxb + 0, gy, kpx, kpy, bxc, byc);
                w.y = sqrtf(fmaxf(q2.y + k2 - 2.0f * dot.y, 0.0f)) * ring_weight(pxb + 1, gy, kpx, kpy, bxc, byc);
                w.z = sqrtf(fmaxf(q2.z + k2 - 2.0f * dot.z, 0.0f)) * ring_weight(pxb + 2, gy, kpx, kpy, bxc, byc);
                w.w = sqrtf(fmaxf(q2.w + k2 - 2.0f * dot.w, 0.0f)) * ring_weight(pxb + 3, gy, kpx, kpy, bxc, byc);
                ((float4*)s_wd)[chunk] = w;
                if (L >= 1 && L <= 16)
                    coarse = vimin(coarse, row4min(w, gy * WW + pxb));
            }
        }
    }

    if (WP) {
        // wave-level coarse partial: shuffle-only, no barrier
        float cv = coarse.v; int ci = coarse.i;
        wave_argmin(cv, ci);
        if ((tid & 63) == 0) parts[(size_t)bn * 32 + yg * 4 + wv] = packvi(cv, ci);
    } else {
        block_argmin_slot(coarse.v, coarse.i, tid, s_rv, s_ri,
                          &parts[(size_t)bn * 16 + yg]);
    }

    __syncthreads();   // publish s_wd (no output stores issued yet)

    VI fine = upsample_stripe(s_wd, bn, yg, tid, out_x4);

    if (WP) {
        float fv = fine.v; int fi = fine.i;
        wave_argmin(fv, fi);
        if ((tid & 63) == 0) parts[(size_t)bn * 32 + 16 + yg * 4 + wv] = packvi(fv, fi);
        // no trailing barrier: block retires with nt-stores in flight
    } else {
        block_argmin_slot(fine.v, fine.i, tid, s_rv, s_ri,
                          &parts[(size_t)bn * 16 + 4 + yg]);
    }
}

// ---------------- Finalize ----------------
// NOTE: no __restrict__ (parts may alias the out_keys region in fallback).
__global__ __launch_bounds__(64) void ee_fin(
    const float* kq,
    const float* mkeys,
    float* out_joints,
    float* out_valid,
    float* out_keys,
    const u64* parts, int pstride, int cnt, int foff)
{
    const int bn   = blockIdx.x;
    const int b    = bn / NKEYS;
    const int lane = threadIdx.x;

    u64 pc = (lane < cnt) ? parts[(size_t)bn * pstride + lane]        : ~0ull;
    u64 pf = (lane < cnt) ? parts[(size_t)bn * pstride + foff + lane] : ~0ull;
    #pragma unroll
    for (int off = 1; off <= 8; off <<= 1) {
        u64 o;
        o = __shfl_xor(pc, off, 64); if (o < pc) pc = o;
        o = __shfl_xor(pf, off, 64); if (o < pf) pf = o;
    }
    pc = __shfl(pc, 0, 64);
    pf = __shfl(pf, 0, 64);

    const float min_d = __uint_as_float((unsigned int)(pc >> 32));
    const int   cbest = (int)(pc & 0xffffffffu);

    const float mv = (lane < CCH) ? mkeys[(size_t)bn * CCH + lane] : 0.0f;
    const bool  nz = __any(mv != 0.0f);
    const bool  valid = nz && ((int)floorf(min_d) <= 5);

    float o = mv;
    if (lane < CCH && valid)
        o = kq[(size_t)(b * CCH + lane) * (HH * WW) + cbest];

    __syncthreads();   // drain loads before (possibly aliasing) stores

    if (lane < CCH) out_keys[(size_t)bn * CCH + lane] = o;
    if (lane == 0) {
        const int fi = (int)(pf & 0xffffffffu);
        out_joints[bn * 2 + 0] = (float)(valid ? (fi >> 8)  : -1);
        out_joints[bn * 2 + 1] = (float)(valid ? (fi & 255) : -1);
        out_valid[bn] = valid ? 1.0f : 0.0f;
    }
}

extern "C" void kernel_launch(void* const* d_in, const int* in_sizes, int n_in,
                              void* d_out, int out_size, void* d_ws, size_t ws_size,
                              hipStream_t stream) {
    const float* kq = (const float*)d_in[0];
    const float* mk = (const float*)d_in[1];
    const int*   mj = (const int*)d_in[2];

    const int B  = in_sizes[1] / (NKEYS * CCH);   // 64
    const int BN = B * NKEYS;                     // 1088

    float* out_f     = (float*)d_out;
    float* o_joints  = out_f;                     // B*N*2
    float* o_valid   = o_joints + BN * 2;         // B*N
    float* o_keys    = o_valid + BN;              // B*N*C
    float* o_x4      = o_keys + BN * CCH;         // B*N*256*256

    if (ws_size >= (size_t)BN * 32 * sizeof(u64)) {
        // Primary: wave-level partials in d_ws, zero reduction barriers.
        u64* parts = (u64*)d_ws;
        ee_merged<true><<<dim3(BN * 4), dim3(256), 0, stream>>>(kq, mk, mj, o_x4, parts);
        ee_fin<<<dim3(BN), dim3(64), 0, stream>>>(kq, mk, o_joints, o_valid, o_keys,
                                                  parts, 32, 16, 16);
    } else {
        // Fallback: block-level partials stashed in each bn's own out_keys slot
        // (BN*16 u64 == out_keys size exactly); ee_fin reads before overwriting.
        u64* parts = (u64*)o_keys;
        ee_merged<false><<<dim3(BN * 4), dim3(256), 0, stream>>>(kq, mk, mj, o_x4, parts);
        ee_fin<<<dim3(BN), dim3(64), 0, stream>>>(kq, mk, o_joints, o_valid, o_keys,
                                                  parts, 16, 4, 4);
    }
}